// Round 2
// baseline (305.114 us; speedup 1.0000x reference)
//
#include <hip/hip_runtime.h>
#include <hip/hip_bf16.h>
#include <stdint.h>

#define NN 4096
#define NF 128
#define NSPLIT 16

using f32x4  = __attribute__((ext_vector_type(4))) float;
using bf16x8 = __attribute__((ext_vector_type(8))) __bf16;
using u16x8  = __attribute__((ext_vector_type(8))) uint16_t;

__device__ __forceinline__ uint16_t f2b(float f) {
    union { float f; uint32_t u; } v; v.f = f;
    uint32_t r = v.u + 0x7FFFu + ((v.u >> 16) & 1u);
    return (uint16_t)(r >> 16);
}

__device__ __forceinline__ void gld_lds16(const void* g, void* l) {
    __builtin_amdgcn_global_load_lds(
        (const __attribute__((address_space(1))) uint32_t*)g,
        (__attribute__((address_space(3))) uint32_t*)l,
        16, 0, 0);
}

// ---------------------------------------------------------------------------
// Kernel 1: XW = X@W, s_col = XW@a[:128], s_row = XW@a[128:], XWT bf16
// ---------------------------------------------------------------------------
__global__ void xw_kernel(const float* __restrict__ X, const float* __restrict__ W,
                          const float* __restrict__ a,
                          uint16_t* __restrict__ XWT,
                          float* __restrict__ s_col, float* __restrict__ s_row) {
    __shared__ float xs[NF];
    __shared__ float red[4];
    const int i = blockIdx.x, f = threadIdx.x;
    xs[f] = X[i * NF + f];
    __syncthreads();
    float acc = 0.f;
    #pragma unroll 8
    for (int k = 0; k < NF; ++k) acc += xs[k] * W[k * NF + f];
    XWT[(size_t)f * NN + i] = f2b(acc);
    float sc = acc * a[f];
    float sr = acc * a[NF + f];
    #pragma unroll
    for (int off = 32; off; off >>= 1) {
        sc += __shfl_down(sc, off);
        sr += __shfl_down(sr, off);
    }
    if ((f & 63) == 0) { red[f >> 6] = sc; red[2 + (f >> 6)] = sr; }
    __syncthreads();
    if (f == 0) {
        s_col[i] = red[0] + red[1];
        s_row[i] = red[2] + red[3];
    }
}

// ---------------------------------------------------------------------------
// Kernel 2: prep — brute-force order statistics (O(N^2) counting, fully parallel)
//   blocks 0..127  : rank of each k by (s_row[k], k); scatter ks/w1s/w2s
//   blocks 128..255: C[j] = #{k : s_row[k] <= -s_col[j]}; ec1/ec2
// 32 targets per block, 8 threads per target (interleaved candidate sets so the
// 8 subs hit distinct bank quads), shuffle-reduce partial counts.
// ---------------------------------------------------------------------------
__global__ __launch_bounds__(256) void prep_kernel(
    const float* __restrict__ s_row, const float* __restrict__ s_col,
    int* __restrict__ ks, float* __restrict__ w1s, float* __restrict__ w2s,
    int* __restrict__ C, float* __restrict__ ec1, float* __restrict__ ec2) {
    __shared__ __align__(16) float sr[NN];
    const int t = threadIdx.x;
    #pragma unroll
    for (int c = 0; c < 16; ++c) sr[t + c * 256] = s_row[t + c * 256];
    __syncthreads();
    const bool isC = blockIdx.x >= 128;
    const int tgt = (blockIdx.x & 127) * 32 + (t >> 3);
    const int sub = t & 7;
    const float4* sr4 = (const float4*)sr;
    int cnt = 0;
    if (!isC) {
        const float s = sr[tgt];
        #pragma unroll 4
        for (int q = 0; q < 128; ++q) {
            const int k4 = q * 8 + sub;          // distinct bank quad per sub
            float4 v = sr4[k4];
            const int kb = k4 * 4;
            cnt += (v.x < s) | ((v.x == s) & (kb + 0 < tgt));
            cnt += (v.y < s) | ((v.y == s) & (kb + 1 < tgt));
            cnt += (v.z < s) | ((v.z == s) & (kb + 2 < tgt));
            cnt += (v.w < s) | ((v.w == s) & (kb + 3 < tgt));
        }
    } else {
        const float th = -s_col[tgt];
        #pragma unroll 4
        for (int q = 0; q < 128; ++q) {
            float4 v = sr4[q * 8 + sub];
            cnt += (v.x <= th) + (v.y <= th) + (v.z <= th) + (v.w <= th);
        }
    }
    cnt += __shfl_down(cnt, 4);
    cnt += __shfl_down(cnt, 2);
    cnt += __shfl_down(cnt, 1);
    if (sub == 0) {
        if (!isC) {
            const float s = sr[tgt];
            ks[cnt]  = tgt;
            w1s[cnt] = __expf(s);
            w2s[cnt] = __expf(0.01f * s);
        } else {
            C[tgt] = cnt;
            const float sc = s_col[tgt];
            ec1[tgt] = __expf(sc);
            ec2[tgt] = __expf(0.01f * sc);
        }
    }
}

// ---------------------------------------------------------------------------
// Kernel 3: per-row exact num/att via dual prefix scan (replaces A@den GEMM).
//   num[i,j] = ec1[j]*(tot1 - P1[C[j]-1]) + ec2[j]*P2[C[j]-1]
//   att[i,j] = den(i,j)/num[i,j],  den = exp(lrelu(s_row[i]+s_col[j]))
// Side effect: writes bf16 copy of A row (replaces conv_kernel's bf16 output).
// P1/P2 padded stride-9 (PIDX) -> conflict-free serial-scan phase.
// ---------------------------------------------------------------------------
#define PIDX(b) ((b) + ((b) >> 3))

__global__ __launch_bounds__(512) void row_kernel(
    const float* __restrict__ A,
    const float* __restrict__ s_row, const float* __restrict__ s_col,
    const int* __restrict__ ks, const float* __restrict__ w1s, const float* __restrict__ w2s,
    const int* __restrict__ C, const float* __restrict__ ec1, const float* __restrict__ ec2,
    uint16_t* __restrict__ Ab, uint16_t* __restrict__ att) {
    __shared__ __align__(16) float rowA[NN];
    __shared__ __align__(16) float P1[4608];
    __shared__ __align__(16) float P2[4608];
    __shared__ float wtot[2][8];
    const int i = blockIdx.x, t = threadIdx.x;

    // 1. stage A row in LDS + emit bf16 copy
    {
        const float4* Ar = (const float4*)(A + (size_t)i * NN);
        ushort4* Abr = (ushort4*)(Ab + (size_t)i * NN);
        #pragma unroll
        for (int c = 0; c < 2; ++c) {
            float4 v = Ar[t + c * 512];
            ((float4*)rowA)[t + c * 512] = v;
            ushort4 o; o.x = f2b(v.x); o.y = f2b(v.y); o.z = f2b(v.z); o.w = f2b(v.w);
            Abr[t + c * 512] = o;
        }
    }
    __syncthreads();

    // 2. gather in sorted order, apply weights
    #pragma unroll
    for (int e = 0; e < 8; ++e) {
        const int b = t + e * 512;
        const float av = rowA[ks[b]];
        P1[PIDX(b)] = av * w1s[b];
        P2[PIDX(b)] = av * w2s[b];
    }
    __syncthreads();

    // 3. dual inclusive scan over 4096 (serial-8 + wave shfl scan + block offsets)
    float l1[8], l2[8];
    float s1 = 0.f, s2 = 0.f;
    const int base = t * 8;
    #pragma unroll
    for (int e = 0; e < 8; ++e) {
        s1 += P1[PIDX(base + e)]; l1[e] = s1;
        s2 += P2[PIDX(base + e)]; l2[e] = s2;
    }
    const int lane = t & 63, wid = t >> 6;
    #pragma unroll
    for (int off = 1; off < 64; off <<= 1) {
        float u1 = __shfl_up(s1, off);
        float u2 = __shfl_up(s2, off);
        if (lane >= off) { s1 += u1; s2 += u2; }
    }
    if (lane == 63) { wtot[0][wid] = s1; wtot[1][wid] = s2; }
    __syncthreads();
    float off1 = 0.f, off2 = 0.f;
    #pragma unroll
    for (int w = 0; w < 7; ++w)
        if (w < wid) { off1 += wtot[0][w]; off2 += wtot[1][w]; }
    const float ex1 = off1 + s1 - l1[7];
    const float ex2 = off2 + s2 - l2[7];
    #pragma unroll
    for (int e = 0; e < 8; ++e) {
        P1[PIDX(base + e)] = ex1 + l1[e];
        P2[PIDX(base + e)] = ex2 + l2[e];
    }
    __syncthreads();

    // 4. per-j num/den/att, vectorized bf16 row write
    const float sri  = s_row[i];
    const float tot1 = P1[PIDX(NN - 1)];
    uint16_t* attR = att + (size_t)i * NN;
    {
        const int j0 = t * 8;
        u16x8 ov;
        #pragma unroll
        for (int e = 0; e < 8; ++e) {
            const int j = j0 + e;
            const int Cm = C[j];
            const float p1 = Cm ? P1[PIDX(Cm - 1)] : 0.f;
            const float p2 = Cm ? P2[PIDX(Cm - 1)] : 0.f;
            const float num = ec1[j] * (tot1 - p1) + ec2[j] * p2;
            float z = sri + s_col[j];
            z = z > 0.f ? z : 0.01f * z;
            const float den = __expf(z);
            const float v = (num != 0.f) ? den * __builtin_amdgcn_rcpf(num) : 0.f;
            ov[e] = f2b(v);
        }
        *(u16x8*)(attR + j0) = ov;
    }
}

// ---------------------------------------------------------------------------
// bf16 GEMM core (m97 structure) for the skinny GEMMs
// ---------------------------------------------------------------------------
__device__ __forceinline__ void gemm_core(
    const uint16_t* __restrict__ Ab, const uint16_t* __restrict__ Bt,
    int bm0, int bn0, int kBeg, int kEnd, int K,
    uint16_t* As, uint16_t* Bs, f32x4 acc[4][4]) {
    const int tid  = threadIdx.x;
    const int lane = tid & 63;
    const int wid  = tid >> 6;
    const int wy   = wid >> 1, wx = wid & 1;
    const int quad = lane >> 4, l16 = lane & 15;
    const int byteoff = tid * 16;
    const int srow    = byteoff >> 6;
    const int scol    = (byteoff & 63) >> 1;

    for (int k0 = kBeg; k0 < kEnd; k0 += 32) {
        __syncthreads();
        gld_lds16(Ab + (size_t)(bm0 +      srow) * K + k0 + scol, (char*)As +        byteoff);
        gld_lds16(Ab + (size_t)(bm0 + 64 + srow) * K + k0 + scol, (char*)As + 4096 + byteoff);
        gld_lds16(Bt + (size_t)(bn0 +      srow) * K + k0 + scol, (char*)Bs +        byteoff);
        gld_lds16(Bt + (size_t)(bn0 + 64 + srow) * K + k0 + scol, (char*)Bs + 4096 + byteoff);
        __syncthreads();
        bf16x8 af[4], bf[4];
        #pragma unroll
        for (int mi = 0; mi < 4; ++mi)
            af[mi] = *(const bf16x8*)((const char*)As + ((wy * 64 + mi * 16 + l16) * 64 + quad * 16));
        #pragma unroll
        for (int ni = 0; ni < 4; ++ni)
            bf[ni] = *(const bf16x8*)((const char*)Bs + ((wx * 64 + ni * 16 + l16) * 64 + quad * 16));
        #pragma unroll
        for (int mi = 0; mi < 4; ++mi)
            #pragma unroll
            for (int ni = 0; ni < 4; ++ni)
                acc[mi][ni] = __builtin_amdgcn_mfma_f32_16x16x32_bf16(af[mi], bf[ni], acc[mi][ni], 0, 0, 0);
    }
}

// ---------------------------------------------------------------------------
// Kernel 5: skinny GEMM split-K, P stored column-major per split: P[split][j][i]
// ---------------------------------------------------------------------------
__global__ __launch_bounds__(256) void gemm_splitk_kernel(
    const uint16_t* __restrict__ Ab, const uint16_t* __restrict__ Bt,
    float* __restrict__ P) {
    __shared__ __align__(16) uint16_t As[128 * 32];
    __shared__ __align__(16) uint16_t Bs[128 * 32];
    const int bm0 = blockIdx.y * 128;
    const int split = blockIdx.z;
    const int chunk = NN / NSPLIT;
    f32x4 acc[4][4];
    #pragma unroll
    for (int mi = 0; mi < 4; ++mi)
        #pragma unroll
        for (int ni = 0; ni < 4; ++ni)
            acc[mi][ni] = (f32x4){0.f, 0.f, 0.f, 0.f};

    gemm_core(Ab, Bt, bm0, 0, split * chunk, (split + 1) * chunk, NN, As, Bs, acc);

    const int lane = threadIdx.x & 63, wid = threadIdx.x >> 6;
    const int wy = wid >> 1, wx = wid & 1;
    const int quad = lane >> 4, l16 = lane & 15;
    float* Pp = P + (size_t)split * (NN * NF);
    #pragma unroll
    for (int mi = 0; mi < 4; ++mi) {
        const int i0 = bm0 + wy * 64 + mi * 16 + quad * 4;
        #pragma unroll
        for (int ni = 0; ni < 4; ++ni) {
            const int j = wx * 64 + ni * 16 + l16;
            *(f32x4*)(Pp + (size_t)j * NN + i0) = acc[mi][ni];
        }
    }
}

// ---------------------------------------------------------------------------
// Reduce kernels (P is [split][j][i] col-major)
// ---------------------------------------------------------------------------
__global__ void reduce_t_kernel(const float* __restrict__ P, uint16_t* __restrict__ M1T) {
    int idx = blockIdx.x * 256 + threadIdx.x;
    float s = 0.f;
    #pragma unroll
    for (int sp = 0; sp < NSPLIT; ++sp) s += P[(size_t)sp * (NN * NF) + idx];
    M1T[idx] = f2b(s);
}

__global__ void reduce_out_kernel(const float* __restrict__ P, float* __restrict__ out) {
    int idx = blockIdx.x * 256 + threadIdx.x;
    float s = 0.f;
    #pragma unroll
    for (int sp = 0; sp < NSPLIT; ++sp) s += P[(size_t)sp * (NN * NF) + idx];
    int j = idx >> 12, i = idx & 4095;
    out[(size_t)i * NF + j] = s;
}

// ---------------------------------------------------------------------------
extern "C" void kernel_launch(void* const* d_in, const int* in_sizes, int n_in,
                              void* d_out, int out_size, void* d_ws, size_t ws_size,
                              hipStream_t stream) {
    (void)in_sizes; (void)n_in; (void)out_size; (void)ws_size;
    const float* X = (const float*)d_in[0];
    const float* A = (const float*)d_in[1];
    const float* W = (const float*)d_in[2];
    const float* a = (const float*)d_in[3];
    float* H = (float*)d_out;

    char* ws = (char*)d_ws;
    uint16_t* Ab  = (uint16_t*)(ws);                       // 32 MB bf16 A
    uint16_t* att = (uint16_t*)(ws + ((size_t)32 << 20));  // 32 MB bf16 att
    float*    P   = (float*)   (ws + ((size_t)64 << 20));  // 32 MB split-K partials
    uint16_t* XWT = (uint16_t*)(ws + ((size_t)96 << 20));  // 1 MB
    uint16_t* M1T = (uint16_t*)(ws + ((size_t)97 << 20));  // 1 MB
    // small arrays live inside P's region (dead before first P write)
    char* sm = ws + ((size_t)64 << 20);
    float* s_col = (float*)(sm);
    float* s_row = (float*)(sm + (16 << 10));
    int*   ks    = (int*)  (sm + (32 << 10));
    float* w1s   = (float*)(sm + (48 << 10));
    float* w2s   = (float*)(sm + (64 << 10));
    int*   C     = (int*)  (sm + (80 << 10));
    float* ec1   = (float*)(sm + (96 << 10));
    float* ec2   = (float*)(sm + (112 << 10));

    // 1. XW + scores (+ XWT bf16)
    xw_kernel<<<NN, NF, 0, stream>>>(X, W, a, XWT, s_col, s_row);
    // 2. order statistics for the exact rank-1 decomposition of den
    prep_kernel<<<256, 256, 0, stream>>>(s_row, s_col, ks, w1s, w2s, C, ec1, ec2);
    // 3. exact num + att per row via dual prefix scan (replaces fp8 A@den GEMM);
    //    also emits bf16 A copy (replaces conv_kernel)
    row_kernel<<<NN, 512, 0, stream>>>(A, s_row, s_col, ks, w1s, w2s, C, ec1, ec2, Ab, att);
    // 4. M1 = att @ XW (split-K partials)
    gemm_splitk_kernel<<<dim3(1, 32, NSPLIT), 256, 0, stream>>>(att, XWT, P);
    // 5. reduce -> M1T bf16 (col-major == B^T operand)
    reduce_t_kernel<<<(NN * NF) / 256, 256, 0, stream>>>(P, M1T);
    // 6. H = A @ M1 (split-K partials)
    gemm_splitk_kernel<<<dim3(1, 32, NSPLIT), 256, 0, stream>>>(Ab, M1T, P);
    // 7. reduce -> output
    reduce_out_kernel<<<(NN * NF) / 256, 256, 0, stream>>>(P, H);
}

// Round 3
// 203.190 us; speedup vs baseline: 1.5016x; 1.5016x over previous
//
#include <hip/hip_runtime.h>
#include <hip/hip_bf16.h>
#include <stdint.h>

#define NN 4096
#define NF 128
#define NSPLIT 16

using f32x4  = __attribute__((ext_vector_type(4))) float;
using bf16x8 = __attribute__((ext_vector_type(8))) __bf16;
using u16x8  = __attribute__((ext_vector_type(8))) uint16_t;

__device__ __forceinline__ uint16_t f2b(float f) {
    union { float f; uint32_t u; } v; v.f = f;
    uint32_t r = v.u + 0x7FFFu + ((v.u >> 16) & 1u);
    return (uint16_t)(r >> 16);
}

__device__ __forceinline__ float b2f(uint16_t u) {
    union { uint32_t u; float f; } v; v.u = ((uint32_t)u) << 16;
    return v.f;
}

__device__ __forceinline__ void gld_lds16(const void* g, void* l) {
    __builtin_amdgcn_global_load_lds(
        (const __attribute__((address_space(1))) uint32_t*)g,
        (__attribute__((address_space(3))) uint32_t*)l,
        16, 0, 0);
}

// ---------------------------------------------------------------------------
// Kernel 1: XW = X@W, s_col = XW@a[:128], s_row = XW@a[128:], XWT bf16
// ---------------------------------------------------------------------------
__global__ void xw_kernel(const float* __restrict__ X, const float* __restrict__ W,
                          const float* __restrict__ a,
                          uint16_t* __restrict__ XWT,
                          float* __restrict__ s_col, float* __restrict__ s_row) {
    __shared__ float xs[NF];
    __shared__ float red[4];
    const int i = blockIdx.x, f = threadIdx.x;
    xs[f] = X[i * NF + f];
    __syncthreads();
    float acc = 0.f;
    #pragma unroll 8
    for (int k = 0; k < NF; ++k) acc += xs[k] * W[k * NF + f];
    XWT[(size_t)f * NN + i] = f2b(acc);
    float sc = acc * a[f];
    float sr = acc * a[NF + f];
    #pragma unroll
    for (int off = 32; off; off >>= 1) {
        sc += __shfl_down(sc, off);
        sr += __shfl_down(sr, off);
    }
    if ((f & 63) == 0) { red[f >> 6] = sc; red[2 + (f >> 6)] = sr; }
    __syncthreads();
    if (f == 0) {
        s_col[i] = red[0] + red[1];
        s_row[i] = red[2] + red[3];
    }
}

// ---------------------------------------------------------------------------
// Kernel 2: prep — brute-force order statistics (O(N^2) counting, fully parallel)
//   blocks 0..127  : rank of each k by (s_row[k], k); scatter ks/w1s/w2s
//   blocks 128..255: rec[j] = {C[j] bitcast, exp(s_col), exp(.01 s_col), s_col}
//                    with C[j] = #{k : s_row[k] <= -s_col[j]}
// ---------------------------------------------------------------------------
__global__ __launch_bounds__(256) void prep_kernel(
    const float* __restrict__ s_row, const float* __restrict__ s_col,
    int* __restrict__ ks, float* __restrict__ w1s, float* __restrict__ w2s,
    float4* __restrict__ rec) {
    __shared__ __align__(16) float sr[NN];
    const int t = threadIdx.x;
    #pragma unroll
    for (int c = 0; c < 16; ++c) sr[t + c * 256] = s_row[t + c * 256];
    __syncthreads();
    const bool isC = blockIdx.x >= 128;
    const int tgt = (blockIdx.x & 127) * 32 + (t >> 3);
    const int sub = t & 7;
    const float4* sr4 = (const float4*)sr;
    int cnt = 0;
    if (!isC) {
        const float s = sr[tgt];
        #pragma unroll 4
        for (int q = 0; q < 128; ++q) {
            const int k4 = q * 8 + sub;          // distinct bank quad per sub
            float4 v = sr4[k4];
            const int kb = k4 * 4;
            cnt += (v.x < s) | ((v.x == s) & (kb + 0 < tgt));
            cnt += (v.y < s) | ((v.y == s) & (kb + 1 < tgt));
            cnt += (v.z < s) | ((v.z == s) & (kb + 2 < tgt));
            cnt += (v.w < s) | ((v.w == s) & (kb + 3 < tgt));
        }
    } else {
        const float th = -s_col[tgt];
        #pragma unroll 4
        for (int q = 0; q < 128; ++q) {
            float4 v = sr4[q * 8 + sub];
            cnt += (v.x <= th) + (v.y <= th) + (v.z <= th) + (v.w <= th);
        }
    }
    cnt += __shfl_down(cnt, 4);
    cnt += __shfl_down(cnt, 2);
    cnt += __shfl_down(cnt, 1);
    if (sub == 0) {
        if (!isC) {
            const float s = sr[tgt];
            ks[cnt]  = tgt;
            w1s[cnt] = __expf(s);
            w2s[cnt] = __expf(0.01f * s);
        } else {
            const float sc = s_col[tgt];
            rec[tgt] = (float4){__int_as_float(cnt), __expf(sc), __expf(0.01f * sc), sc};
        }
    }
}

// ---------------------------------------------------------------------------
// Kernel 3: per-row exact num/att via dual scan (replaces A@den GEMM).
//   num[i,j] = ec1[j]*SUF1[C[j]] + ec2[j]*PRE2[C[j]]   (suffix/prefix stored
//   directly in bf16 -> no cancellation, half the LDS)
//   att[i,j] = den(i,j)/num[i,j],  den = exp(lrelu(s_row[i]+s_col[j]))
// Side effect: bf16 copy of A row.
// LDS 35 KB -> 4 blocks/CU (100% occupancy); launch_bounds pins VGPR<=64.
// ---------------------------------------------------------------------------
#define PB(b) ((b) + (((b) >> 4) << 1))   // +4B pad per 16 elements, keeps pairs adjacent & aligned

__global__ __launch_bounds__(512, 8) void row_kernel(
    const float* __restrict__ A,
    const float* __restrict__ s_row,
    const int* __restrict__ ks, const float* __restrict__ w1s, const float* __restrict__ w2s,
    const float4* __restrict__ rec,
    uint16_t* __restrict__ Ab, uint16_t* __restrict__ att) {
    __shared__ __align__(16) float rowA[NN];                 // 16384 B
    __shared__ __align__(16) uint16_t S1[4640];              // 9280 B  (SUF1, bf16, padded)
    __shared__ __align__(16) uint16_t S2[4640];              // 9280 B  (PRE2, bf16, padded)
    __shared__ float wtot[2][8];
    const int i = blockIdx.x, t = threadIdx.x;

    // 1. stage A row (fp32) + emit bf16 copy
    {
        const float4* Ar = (const float4*)(A + (size_t)i * NN);
        ushort4* Abr = (ushort4*)(Ab + (size_t)i * NN);
        #pragma unroll
        for (int c = 0; c < 2; ++c) {
            float4 v = Ar[t + c * 512];
            ((float4*)rowA)[t + c * 512] = v;
            ushort4 o; o.x = f2b(v.x); o.y = f2b(v.y); o.z = f2b(v.z); o.w = f2b(v.w);
            Abr[t + c * 512] = o;
        }
    }
    __syncthreads();

    // 2. gather own 8 sorted elements straight into registers, dual local prefix
    float l1[8], l2[8];
    {
        const int4*   k4 = (const int4*)ks;
        const float4* a4 = (const float4*)w1s;
        const float4* b4 = (const float4*)w2s;
        float run1 = 0.f, run2 = 0.f;
        #pragma unroll
        for (int g = 0; g < 2; ++g) {
            int4   kk = k4[2 * t + g];
            float4 wa = a4[2 * t + g];
            float4 wb = b4[2 * t + g];
            float g0 = rowA[kk.x], g1 = rowA[kk.y], g2 = rowA[kk.z], g3 = rowA[kk.w];
            run1 += g0 * wa.x; l1[4 * g + 0] = run1;  run2 += g0 * wb.x; l2[4 * g + 0] = run2;
            run1 += g1 * wa.y; l1[4 * g + 1] = run1;  run2 += g1 * wb.y; l2[4 * g + 1] = run2;
            run1 += g2 * wa.z; l1[4 * g + 2] = run1;  run2 += g2 * wb.z; l2[4 * g + 2] = run2;
            run1 += g3 * wa.w; l1[4 * g + 3] = run1;  run2 += g3 * wb.w; l2[4 * g + 3] = run2;
        }
    }
    float s1 = l1[7], s2 = l2[7];
    const int lane = t & 63, wid = t >> 6;
    #pragma unroll
    for (int off = 1; off < 64; off <<= 1) {
        float u1 = __shfl_up(s1, off);
        float u2 = __shfl_up(s2, off);
        if (lane >= off) { s1 += u1; s2 += u2; }
    }
    if (lane == 63) { wtot[0][wid] = s1; wtot[1][wid] = s2; }
    __syncthreads();

    // 3. cross-wave offsets + totals; write SUF1/PRE2 as packed bf16 pairs
    float off1 = 0.f, off2 = 0.f, tot1 = 0.f, tot2 = 0.f;
    #pragma unroll
    for (int w = 0; w < 8; ++w) {
        const float va = wtot[0][w], vb = wtot[1][w];
        tot1 += va; tot2 += vb;
        if (w < wid) { off1 += va; off2 += vb; }
    }
    const float ex1 = off1 + s1 - l1[7];   // exclusive prefix (threads before me), array 1
    const float ex2 = off2 + s2 - l2[7];
    {
        uint32_t* q1 = (uint32_t*)S1;
        uint32_t* q2 = (uint32_t*)S2;
        const int qb = t * 4 + (t >> 1);   // PB(8t)/2
        #pragma unroll
        for (int m = 0; m < 4; ++m) {
            const float pl1 = m ? l1[2 * m - 1] : 0.f;   // l1[e-1] for e=2m
            const float pl2 = m ? l2[2 * m - 1] : 0.f;
            const float sa = tot1 - ex1 - pl1;           // SUF1[8t+2m]
            const float sb = tot1 - ex1 - l1[2 * m];     // SUF1[8t+2m+1]
            const float pa = ex2 + pl2;                  // PRE2[8t+2m]
            const float pb = ex2 + l2[2 * m];            // PRE2[8t+2m+1]
            q1[qb + m] = (uint32_t)f2b(sa) | ((uint32_t)f2b(sb) << 16);
            q2[qb + m] = (uint32_t)f2b(pa) | ((uint32_t)f2b(pb) << 16);
        }
    }
    if (t == 511) {                        // tail entry C = 4096
        S1[PB(4096)] = 0;                  // empty suffix
        S2[PB(4096)] = f2b(tot2);          // full prefix
    }
    __syncthreads();

    // 4. per-j att: fully-coalesced rec loads, packed-bf16 u32 stores
    const float sri = s_row[i];
    uint32_t* attR = (uint32_t*)(att + (size_t)i * NN);
    #pragma unroll
    for (int e = 0; e < 4; ++e) {
        const int j0 = e * 1024 + 2 * t;
        const float4 ra = rec[j0];
        const float4 rb = rec[j0 + 1];
        const int Ca = __float_as_int(ra.x);
        const int Cb = __float_as_int(rb.x);
        const float numa = ra.y * b2f(S1[PB(Ca)]) + ra.z * b2f(S2[PB(Ca)]);
        const float numb = rb.y * b2f(S1[PB(Cb)]) + rb.z * b2f(S2[PB(Cb)]);
        float za = sri + ra.w; za = za > 0.f ? za : 0.01f * za;
        float zb = sri + rb.w; zb = zb > 0.f ? zb : 0.01f * zb;
        const float dena = __expf(za);
        const float denb = __expf(zb);
        const float va = (numa != 0.f) ? dena * __builtin_amdgcn_rcpf(numa) : 0.f;
        const float vb = (numb != 0.f) ? denb * __builtin_amdgcn_rcpf(numb) : 0.f;
        attR[e * 512 + t] = (uint32_t)f2b(va) | ((uint32_t)f2b(vb) << 16);
    }
}

// ---------------------------------------------------------------------------
// bf16 GEMM core (m97 structure) for the skinny GEMMs
// ---------------------------------------------------------------------------
__device__ __forceinline__ void gemm_core(
    const uint16_t* __restrict__ Ab, const uint16_t* __restrict__ Bt,
    int bm0, int bn0, int kBeg, int kEnd, int K,
    uint16_t* As, uint16_t* Bs, f32x4 acc[4][4]) {
    const int tid  = threadIdx.x;
    const int lane = tid & 63;
    const int wid  = tid >> 6;
    const int wy   = wid >> 1, wx = wid & 1;
    const int quad = lane >> 4, l16 = lane & 15;
    const int byteoff = tid * 16;
    const int srow    = byteoff >> 6;
    const int scol    = (byteoff & 63) >> 1;

    for (int k0 = kBeg; k0 < kEnd; k0 += 32) {
        __syncthreads();
        gld_lds16(Ab + (size_t)(bm0 +      srow) * K + k0 + scol, (char*)As +        byteoff);
        gld_lds16(Ab + (size_t)(bm0 + 64 + srow) * K + k0 + scol, (char*)As + 4096 + byteoff);
        gld_lds16(Bt + (size_t)(bn0 +      srow) * K + k0 + scol, (char*)Bs +        byteoff);
        gld_lds16(Bt + (size_t)(bn0 + 64 + srow) * K + k0 + scol, (char*)Bs + 4096 + byteoff);
        __syncthreads();
        bf16x8 af[4], bf[4];
        #pragma unroll
        for (int mi = 0; mi < 4; ++mi)
            af[mi] = *(const bf16x8*)((const char*)As + ((wy * 64 + mi * 16 + l16) * 64 + quad * 16));
        #pragma unroll
        for (int ni = 0; ni < 4; ++ni)
            bf[ni] = *(const bf16x8*)((const char*)Bs + ((wx * 64 + ni * 16 + l16) * 64 + quad * 16));
        #pragma unroll
        for (int mi = 0; mi < 4; ++mi)
            #pragma unroll
            for (int ni = 0; ni < 4; ++ni)
                acc[mi][ni] = __builtin_amdgcn_mfma_f32_16x16x32_bf16(af[mi], bf[ni], acc[mi][ni], 0, 0, 0);
    }
}

// ---------------------------------------------------------------------------
// Kernel 5: skinny GEMM split-K, P stored column-major per split: P[split][j][i]
// ---------------------------------------------------------------------------
__global__ __launch_bounds__(256) void gemm_splitk_kernel(
    const uint16_t* __restrict__ Ab, const uint16_t* __restrict__ Bt,
    float* __restrict__ P) {
    __shared__ __align__(16) uint16_t As[128 * 32];
    __shared__ __align__(16) uint16_t Bs[128 * 32];
    const int bm0 = blockIdx.y * 128;
    const int split = blockIdx.z;
    const int chunk = NN / NSPLIT;
    f32x4 acc[4][4];
    #pragma unroll
    for (int mi = 0; mi < 4; ++mi)
        #pragma unroll
        for (int ni = 0; ni < 4; ++ni)
            acc[mi][ni] = (f32x4){0.f, 0.f, 0.f, 0.f};

    gemm_core(Ab, Bt, bm0, 0, split * chunk, (split + 1) * chunk, NN, As, Bs, acc);

    const int lane = threadIdx.x & 63, wid = threadIdx.x >> 6;
    const int wy = wid >> 1, wx = wid & 1;
    const int quad = lane >> 4, l16 = lane & 15;
    float* Pp = P + (size_t)split * (NN * NF);
    #pragma unroll
    for (int mi = 0; mi < 4; ++mi) {
        const int i0 = bm0 + wy * 64 + mi * 16 + quad * 4;
        #pragma unroll
        for (int ni = 0; ni < 4; ++ni) {
            const int j = wx * 64 + ni * 16 + l16;
            *(f32x4*)(Pp + (size_t)j * NN + i0) = acc[mi][ni];
        }
    }
}

// ---------------------------------------------------------------------------
// Reduce kernels (P is [split][j][i] col-major)
// ---------------------------------------------------------------------------
__global__ void reduce_t_kernel(const float* __restrict__ P, uint16_t* __restrict__ M1T) {
    int idx = blockIdx.x * 256 + threadIdx.x;
    float s = 0.f;
    #pragma unroll
    for (int sp = 0; sp < NSPLIT; ++sp) s += P[(size_t)sp * (NN * NF) + idx];
    M1T[idx] = f2b(s);
}

__global__ void reduce_out_kernel(const float* __restrict__ P, float* __restrict__ out) {
    int idx = blockIdx.x * 256 + threadIdx.x;
    float s = 0.f;
    #pragma unroll
    for (int sp = 0; sp < NSPLIT; ++sp) s += P[(size_t)sp * (NN * NF) + idx];
    int j = idx >> 12, i = idx & 4095;
    out[(size_t)i * NF + j] = s;
}

// ---------------------------------------------------------------------------
extern "C" void kernel_launch(void* const* d_in, const int* in_sizes, int n_in,
                              void* d_out, int out_size, void* d_ws, size_t ws_size,
                              hipStream_t stream) {
    (void)in_sizes; (void)n_in; (void)out_size; (void)ws_size;
    const float* X = (const float*)d_in[0];
    const float* A = (const float*)d_in[1];
    const float* W = (const float*)d_in[2];
    const float* a = (const float*)d_in[3];
    float* H = (float*)d_out;

    char* ws = (char*)d_ws;
    uint16_t* Ab  = (uint16_t*)(ws);                       // 32 MB bf16 A
    uint16_t* att = (uint16_t*)(ws + ((size_t)32 << 20));  // 32 MB bf16 att
    float*    P   = (float*)   (ws + ((size_t)64 << 20));  // 32 MB split-K partials
    uint16_t* XWT = (uint16_t*)(ws + ((size_t)96 << 20));  // 1 MB
    uint16_t* M1T = (uint16_t*)(ws + ((size_t)97 << 20));  // 1 MB
    // small arrays live inside P's region (dead before first P write)
    char* sm = ws + ((size_t)64 << 20);
    float*  s_col = (float*) (sm);
    float*  s_row = (float*) (sm + (16 << 10));
    int*    ks    = (int*)   (sm + (32 << 10));
    float*  w1s   = (float*) (sm + (48 << 10));
    float*  w2s   = (float*) (sm + (64 << 10));
    float4* rec   = (float4*)(sm + (80 << 10));            // 64 KB {C, ec1, ec2, s_col}

    // 1. XW + scores (+ XWT bf16)
    xw_kernel<<<NN, NF, 0, stream>>>(X, W, a, XWT, s_col, s_row);
    // 2. order statistics for the exact rank-1 decomposition of den
    prep_kernel<<<256, 256, 0, stream>>>(s_row, s_col, ks, w1s, w2s, rec);
    // 3. exact num + att per row via dual scan (also emits bf16 A copy)
    row_kernel<<<NN, 512, 0, stream>>>(A, s_row, ks, w1s, w2s, rec, Ab, att);
    // 4. M1 = att @ XW (split-K partials)
    gemm_splitk_kernel<<<dim3(1, 32, NSPLIT), 256, 0, stream>>>(att, XWT, P);
    // 5. reduce -> M1T bf16 (col-major == B^T operand)
    reduce_t_kernel<<<(NN * NF) / 256, 256, 0, stream>>>(P, M1T);
    // 6. H = A @ M1 (split-K partials)
    gemm_splitk_kernel<<<dim3(1, 32, NSPLIT), 256, 0, stream>>>(Ab, M1T, P);
    // 7. reduce -> output
    reduce_out_kernel<<<(NN * NF) / 256, 256, 0, stream>>>(P, H);
}